// Round 1
// baseline (995.914 us; speedup 1.0000x reference)
//
#include <hip/hip_runtime.h>
#include <hip/hip_bf16.h>
#include <stdint.h>

// Problem: T=128, B=32, D=1024, H=1024 LSTM unroll, fp32 in/out.
#define T_STEPS 128
#define BATCH   32
#define DIM     1024
#define HID     1024
#define NGATE   4096            // 4*H
#define MROWS   4096            // T*B
#define NWGR    32              // persistent recurrence workgroups

typedef unsigned int u32;
typedef __attribute__((ext_vector_type(8)))  __bf16 bf16x8;
typedef __attribute__((ext_vector_type(4)))  float  f32x4;
typedef __attribute__((ext_vector_type(16))) float  f32x16;
typedef __attribute__((ext_vector_type(4)))  u32    u32x4;

__device__ __forceinline__ unsigned short f2bf(float f) {
    u32 x = __float_as_uint(f);
    return (unsigned short)((x + 0x7fffu + ((x >> 16) & 1u)) >> 16);  // RNE
}
__device__ __forceinline__ float sigf(float x) {
    return 1.0f / (1.0f + __expf(-x));
}
__device__ __forceinline__ float tanh_fast(float x) {
    float ax = fabsf(x);
    float e  = __expf(-2.0f * ax);           // in (0,1], no overflow
    float t  = (1.0f - e) / (1.0f + e);
    return copysignf(t, x);
}
__device__ __forceinline__ u32 umax2(u32 a, u32 b) { return a > b ? a : b; }

// DEVICE-scope (agent) store: sc1 only (gfx94x: SC1:SC0 = 10 = device).
// Bypasses L1 + per-XCD L2, served by the memory-side Infinity Cache.
// hb is ONLY touched through sc1 ops during lstm_rec -> no line of it ever
// lives in any L2 -> no acquire fences / buffer_inv needed anywhere.
__device__ __forceinline__ void store_u32_coh(u32* p, u32 v) {
    asm volatile("global_store_dword %0, %1, off sc1" :: "v"(p), "v"(v) : "memory");
}

// ---------------- prep kernels ----------------

__global__ void cast_f32_bf16(const float* __restrict__ in,
                              unsigned short* __restrict__ out, int n) {
    int idx = (blockIdx.x * blockDim.x + threadIdx.x) * 4;
    if (idx + 3 < n) {
        float4 v = *(const float4*)(in + idx);
        ushort4 o;
        o.x = f2bf(v.x); o.y = f2bf(v.y); o.z = f2bf(v.z); o.w = f2bf(v.w);
        *(ushort4*)(out + idx) = o;
    }
}

// sentinel fill: 0xFFFFFFFF = packed (NaN|NaN) bf16 pair; h is always finite
// and in (-1,1), so a real packed h can never equal the sentinel.
__global__ void fill_sentinel(u32* __restrict__ p, int n) {
    int i = (blockIdx.x * blockDim.x + threadIdx.x) * 4;
    if (i + 3 < n) {
        u32x4 v = {0xFFFFFFFFu, 0xFFFFFFFFu, 0xFFFFFFFFu, 0xFFFFFFFFu};
        *(u32x4*)(p + i) = v;
    }
}

// in: R x C fp32 (row-major) -> out: C x R bf16 (row-major transpose)
__global__ void transpose_cast(const float* __restrict__ in,
                               unsigned short* __restrict__ out, int R, int C) {
    __shared__ float tile[32][33];
    int c0 = blockIdx.x * 32, r0 = blockIdx.y * 32;
    int tx = threadIdx.x, ty = threadIdx.y;     // 32 x 8
#pragma unroll
    for (int i = 0; i < 4; ++i)
        tile[ty + i * 8][tx] = in[(size_t)(r0 + ty + i * 8) * C + c0 + tx];
    __syncthreads();
#pragma unroll
    for (int i = 0; i < 4; ++i)
        out[(size_t)(c0 + ty + i * 8) * R + r0 + tx] = f2bf(tile[tx][ty + i * 8]);
}

// ---------------- phase 1: Gp = perm(x @ Wx + b)  (bf16 MFMA, fp32 out) ----------------
// A: MROWS x DIM bf16 (x), BT: NGATE x DIM bf16 (WxT).
// Output written in recurrence-friendly permuted panels:
//   orig col co = g*1024 + hu  ->  panel wg = hu>>5, local col cp = g*32 + (hu&31)
//   Gp[((wg*MROWS)+row)*128 + cp]
__global__ __launch_bounds__(256) void gemm_xw(
    const unsigned short* __restrict__ A,
    const unsigned short* __restrict__ BT,
    const float* __restrict__ bias,
    float* __restrict__ Gp) {
    __shared__ unsigned short As[128 * 32];
    __shared__ unsigned short Bs[128 * 32];
    int tid  = threadIdx.x;
    int wave = tid >> 6, lane = tid & 63;
    int q = lane >> 4, c = lane & 15;
    int wm = wave >> 1, wn = wave & 1;
    int tm = blockIdx.y * 128, tn = blockIdx.x * 128;

    f32x4 acc[4][4] = {};

    const int srow0 = tid >> 2;           // 0..63
    const int srow1 = 64 + (tid >> 2);    // 64..127
    const int scol  = (tid & 3) * 8;      // bf16 elems

    u32x4 ra0, ra1, rb0, rb1;
    ra0 = *(const u32x4*)(A  + (size_t)(tm + srow0) * DIM + scol);
    ra1 = *(const u32x4*)(A  + (size_t)(tm + srow1) * DIM + scol);
    rb0 = *(const u32x4*)(BT + (size_t)(tn + srow0) * DIM + scol);
    rb1 = *(const u32x4*)(BT + (size_t)(tn + srow1) * DIM + scol);

    for (int kk = 0; kk < 32; ++kk) {
        __syncthreads();
        *(u32x4*)(As + srow0 * 32 + scol) = ra0;
        *(u32x4*)(As + srow1 * 32 + scol) = ra1;
        *(u32x4*)(Bs + srow0 * 32 + scol) = rb0;
        *(u32x4*)(Bs + srow1 * 32 + scol) = rb1;
        __syncthreads();
        if (kk < 31) {
            int ko = (kk + 1) * 32 + scol;
            ra0 = *(const u32x4*)(A  + (size_t)(tm + srow0) * DIM + ko);
            ra1 = *(const u32x4*)(A  + (size_t)(tm + srow1) * DIM + ko);
            rb0 = *(const u32x4*)(BT + (size_t)(tn + srow0) * DIM + ko);
            rb1 = *(const u32x4*)(BT + (size_t)(tn + srow1) * DIM + ko);
        }
        bf16x8 af[4], bfv[4];
#pragma unroll
        for (int i = 0; i < 4; ++i) {
            af[i]  = *(const bf16x8*)(As + (wm * 64 + i * 16 + c) * 32 + q * 8);
            bfv[i] = *(const bf16x8*)(Bs + (wn * 64 + i * 16 + c) * 32 + q * 8);
        }
#pragma unroll
        for (int i = 0; i < 4; ++i)
#pragma unroll
            for (int j = 0; j < 4; ++j)
                acc[i][j] = __builtin_amdgcn_mfma_f32_16x16x32_bf16(
                    af[i], bfv[j], acc[i][j], 0, 0, 0);
    }
    // epilogue: C/D layout col = lane&15, row = quad*4 + reg; permuted store
#pragma unroll
    for (int j = 0; j < 4; ++j) {
        int co = tn + wn * 64 + j * 16 + c;
        float bj = bias[co];
        int g = co >> 10, hu = co & 1023;
        int wgr = hu >> 5, u = hu & 31;
        int cp = g * 32 + u;
#pragma unroll
        for (int i = 0; i < 4; ++i) {
            int row0 = tm + wm * 64 + i * 16 + q * 4;
#pragma unroll
            for (int r = 0; r < 4; ++r)
                Gp[((size_t)wgr * MROWS + row0 + r) * 128 + cp] = acc[i][j][r] + bj;
        }
    }
}

// ---------------- phase 2: persistent recurrence ----------------
// 32 WGs x 512 threads (8 waves). WG wg owns hidden units [wg*32, wg*32+32) -> 128
// permuted gate cols. Wave wv: cg = wv&1 (2x 32-col tiles), ks = wv>>1 (K-split,
// 256 of 1024). Wh fragments live in registers for all 128 steps.
//
// SENTINEL PROTOCOL (replaces flags): hb is pre-filled with 0xFFFFFFFF (packed
// NaN|NaN -- unreachable for real h in (-1,1)). Each hb slot is written exactly
// once. The consumer "poll" IS the data load: issue the 16 h-loads, vmcnt(0),
// then a 64-word v_max_u32 tree; if any word is still the sentinel, reload.
// This removes, per step: the producer's store-ack vmcnt(0), the flag store,
// one full __syncthreads, AND the separate flag-poll IC round-trip -- the
// handshake collapses from 3 serial IC round-trips to 1. Validation is
// per-word, so no ordering/fence semantics are needed anywhere.
// Barriers are raw s_barrier + lgkmcnt(0)-only waits (LDS publish), so the
// compiler's vmcnt(0)-draining __syncthreads no longer serializes the Gp
// prefetch / out-store against the critical path.
__global__ __launch_bounds__(512, 1) void lstm_rec(
    const unsigned short* __restrict__ WhT,   // NGATE x DIM bf16
    const float* __restrict__ Gp,             // permuted gates, 32 x 4096 x 128 fp32
    unsigned short* hb,                       // (T+1) x BATCH x HID bf16 (slot 0 unused)
    float* __restrict__ out) {                // T x BATCH x HID fp32
    __shared__ float Gl[2][32][133];          // double-buffered G slice (pad 133)
    __shared__ float SlT[4][128][33];         // K-split partials, transposed (pad 33)
    const int wg = blockIdx.x, tid = threadIdx.x;
    const int wv = tid >> 6, lane = tid & 63;
    const int cg = wv & 1, ks = wv >> 1;
    const int ln = lane & 31, lh = lane >> 5;

    // ---- stage B-fragments (Wh) into registers, once ----
    bf16x8 br0[16], br1[16];
    {
        const unsigned short* w0 =
            WhT + (size_t)((cg * 2 + 0) * HID + wg * 32 + ln) * DIM + ks * 256 + lh * 8;
        const unsigned short* w1 =
            WhT + (size_t)((cg * 2 + 1) * HID + wg * 32 + ln) * DIM + ks * 256 + lh * 8;
#pragma unroll
        for (int kk = 0; kk < 16; ++kk) {
            br0[kk] = *(const bf16x8*)(w0 + kk * 16);
            br1[kk] = *(const bf16x8*)(w1 + kk * 16);
        }
    }

    // ---- G slice for t=0 into Gl[0] ----
    {
        const float* p = Gp + (size_t)wg * MROWS * 128 + tid * 8;
        f32x4 a = *(const f32x4*)p, b2 = *(const f32x4*)(p + 4);
        float* d = &Gl[0][tid >> 4][(tid & 15) * 8];
#pragma unroll
        for (int i = 0; i < 4; ++i) { d[i] = a[i]; d[4 + i] = b2[i]; }
    }
    __syncthreads();

    // epilogue mapping: thread = (batch, uu); owns units 2*uu, 2*uu+1
    const int batch = tid >> 4, uu = tid & 15;
    float cs0 = 0.f, cs1 = 0.f;
    f32x4 ga = {}, gb = {};

    for (int t = 0; t < T_STEPS; ++t) {
        const int cur = t & 1;

        // ---- K-phase: self-validating h-load (poll == data load) + 32 MFMAs ----
        f32x16 acc0 = {}, acc1 = {};
        if (t > 0) {
            const unsigned short* hbase = hb + (size_t)t * (BATCH * HID)
                                        + (size_t)ln * HID + ks * 256 + lh * 8;
            u32x4 h[16];
            for (;;) {
                asm volatile(
                    "global_load_dwordx4 %0,  %16, off sc1\n\t"
                    "global_load_dwordx4 %1,  %16, off offset:32 sc1\n\t"
                    "global_load_dwordx4 %2,  %16, off offset:64 sc1\n\t"
                    "global_load_dwordx4 %3,  %16, off offset:96 sc1\n\t"
                    "global_load_dwordx4 %4,  %16, off offset:128 sc1\n\t"
                    "global_load_dwordx4 %5,  %16, off offset:160 sc1\n\t"
                    "global_load_dwordx4 %6,  %16, off offset:192 sc1\n\t"
                    "global_load_dwordx4 %7,  %16, off offset:224 sc1\n\t"
                    "global_load_dwordx4 %8,  %16, off offset:256 sc1\n\t"
                    "global_load_dwordx4 %9,  %16, off offset:288 sc1\n\t"
                    "global_load_dwordx4 %10, %16, off offset:320 sc1\n\t"
                    "global_load_dwordx4 %11, %16, off offset:352 sc1\n\t"
                    "global_load_dwordx4 %12, %16, off offset:384 sc1\n\t"
                    "global_load_dwordx4 %13, %16, off offset:416 sc1\n\t"
                    "global_load_dwordx4 %14, %16, off offset:448 sc1\n\t"
                    "global_load_dwordx4 %15, %16, off offset:480 sc1\n\t"
                    "s_waitcnt vmcnt(0)"
                    : "=&v"(h[0]),  "=&v"(h[1]),  "=&v"(h[2]),  "=&v"(h[3]),
                      "=&v"(h[4]),  "=&v"(h[5]),  "=&v"(h[6]),  "=&v"(h[7]),
                      "=&v"(h[8]),  "=&v"(h[9]),  "=&v"(h[10]), "=&v"(h[11]),
                      "=&v"(h[12]), "=&v"(h[13]), "=&v"(h[14]), "=&v"(h[15])
                    : "v"(hbase)
                    : "memory");
                // sentinel check: max over all 64 words == 0xFFFFFFFF iff any
                // word is still unwritten (real packed h can't be NaN|NaN).
                u32 m = 0;
#pragma unroll
                for (int i = 0; i < 16; ++i) {
                    u32 a = umax2(umax2(h[i][0], h[i][1]),
                                  umax2(h[i][2], h[i][3]));
                    m = umax2(m, a);
                }
                if (!__any((int)(m == 0xFFFFFFFFu))) break;
            }

#pragma unroll
            for (int jj = 0; jj < 8; ++jj) {
                bf16x8 a0 = __builtin_bit_cast(bf16x8, h[2 * jj]);
                bf16x8 a1 = __builtin_bit_cast(bf16x8, h[2 * jj + 1]);
                acc0 = __builtin_amdgcn_mfma_f32_32x32x16_bf16(a0, br0[jj * 2],     acc0, 0, 0, 0);
                acc1 = __builtin_amdgcn_mfma_f32_32x32x16_bf16(a0, br1[jj * 2],     acc1, 0, 0, 0);
                acc0 = __builtin_amdgcn_mfma_f32_32x32x16_bf16(a1, br0[jj * 2 + 1], acc0, 0, 0, 0);
                acc1 = __builtin_amdgcn_mfma_f32_32x32x16_bf16(a1, br1[jj * 2 + 1], acc1, 0, 0, 0);
            }
        }

        // ---- K-split partials into LDS (scalar, conflict-free at pad 33) ----
        // C layout 32x32: col = lane&31, row = (reg&3) + 8*(reg>>2) + 4*(lane>>5)
#pragma unroll
        for (int rg = 0; rg < 4; ++rg)
#pragma unroll
            for (int rr = 0; rr < 4; ++rr) {
                SlT[ks][cg * 64 + ln]     [rg * 8 + lh * 4 + rr] = acc0[rg * 4 + rr];
                SlT[ks][cg * 64 + 32 + ln][rg * 8 + lh * 4 + rr] = acc1[rg * 4 + rr];
            }
        if (t > 0) {   // Gl[cur] for t==0 was pre-filled; ga/gb holds slice t
            float* d = &Gl[cur][tid >> 4][(tid & 15) * 8];
#pragma unroll
            for (int i = 0; i < 4; ++i) { d[i] = ga[i]; d[4 + i] = gb[i]; }
        }
        // publish LDS writes only (no vmcnt drain: raw barrier, not __syncthreads)
        asm volatile("s_waitcnt lgkmcnt(0)" ::: "memory");
        __builtin_amdgcn_s_barrier();

        // ---- epilogue: units u0 = 2*uu, u1 = 2*uu+1 of batch ----
        float gv0[4], gv1[4];
#pragma unroll
        for (int g = 0; g < 4; ++g) {
            const int c0 = g * 32 + 2 * uu, c1 = c0 + 1;
            gv0[g] = Gl[cur][batch][c0] + SlT[0][c0][batch] + SlT[1][c0][batch]
                                        + SlT[2][c0][batch] + SlT[3][c0][batch];
            gv1[g] = Gl[cur][batch][c1] + SlT[0][c1][batch] + SlT[1][c1][batch]
                                        + SlT[2][c1][batch] + SlT[3][c1][batch];
        }
        float cn0 = sigf(gv0[1]) * cs0 + sigf(gv0[0]) * tanh_fast(gv0[2]);
        float cn1 = sigf(gv1[1]) * cs1 + sigf(gv1[0]) * tanh_fast(gv1[2]);
        cs0 = cn0; cs1 = cn1;
        float hv0 = sigf(gv0[3]) * tanh_fast(cn0);
        float hv1 = sigf(gv1[3]) * tanh_fast(cn1);
        u32 packed = (u32)f2bf(hv0) | ((u32)f2bf(hv1) << 16);
        // broadcast h: fire-and-forget sc1 store; consumers self-validate.
        store_u32_coh((u32*)(hb + (size_t)(t + 1) * (BATCH * HID)
                                + (size_t)batch * HID + wg * 32 + 2 * uu), packed);

        // off the critical path: G prefetch for step t+1 + out-store
        // (these drain inside the next step's poll vmcnt(0), overlapped with
        // the IC latency we're waiting on anyway)
        if (t + 1 < T_STEPS) {
            const float* p = Gp + ((size_t)wg * MROWS + (size_t)(t + 1) * 32) * 128 + tid * 8;
            ga = *(const f32x4*)p; gb = *(const f32x4*)(p + 4);
        }
        *(float2*)(out + ((size_t)t * BATCH + batch) * HID + wg * 32 + 2 * uu) =
            make_float2(hv0, hv1);

        // order epilogue LDS reads vs next step's SlT/Gl writes (exec barrier;
        // lgkm already drained by value consumption, wait is ~free)
        asm volatile("s_waitcnt lgkmcnt(0)" ::: "memory");
        __builtin_amdgcn_s_barrier();
    }
}

// ---------------- launch ----------------

extern "C" void kernel_launch(void* const* d_in, const int* in_sizes, int n_in,
                              void* d_out, int out_size, void* d_ws, size_t ws_size,
                              hipStream_t stream) {
    const float* x  = (const float*)d_in[0];   // T*B*D
    const float* Wx = (const float*)d_in[1];   // D x 4H
    const float* Wh = (const float*)d_in[2];   // H x 4H
    const float* b  = (const float*)d_in[3];   // 4H
    float* out = (float*)d_out;

    // workspace layout (bytes)
    char* ws = (char*)d_ws;
    const size_t OFF_XBF  = 0;                       // 8 MB  (4096x1024 bf16)
    const size_t OFF_WXT  = 8ull  << 20;             // 8 MB  (4096x1024 bf16)
    const size_t OFF_WHT  = 16ull << 20;             // 8 MB  (4096x1024 bf16)
    const size_t OFF_G    = 24ull << 20;             // 64 MB (32x4096x128 fp32 permuted)
    const size_t OFF_HB   = 88ull << 20;             // 129 * 64 KB = 8.0625 MB
    const size_t NEEDED   = OFF_HB + (size_t)(T_STEPS + 1) * BATCH * HID * 2;
    if (ws_size < NEEDED) return;  // loud failure (output stays poisoned)

    unsigned short* xbf = (unsigned short*)(ws + OFF_XBF);
    unsigned short* WxT = (unsigned short*)(ws + OFF_WXT);
    unsigned short* WhT = (unsigned short*)(ws + OFF_WHT);
    float*          Gp  = (float*)(ws + OFF_G);
    unsigned short* hb  = (unsigned short*)(ws + OFF_HB);

    // prep
    cast_f32_bf16<<<(MROWS * DIM / 4 + 255) / 256, 256, 0, stream>>>(x, xbf, MROWS * DIM);
    const int HBW = (T_STEPS + 1) * BATCH * HID / 2;    // u32 words in hb
    fill_sentinel<<<(HBW / 4 + 255) / 256, 256, 0, stream>>>((u32*)hb, HBW);
    dim3 tb(32, 8);
    transpose_cast<<<dim3(NGATE / 32, DIM / 32), tb, 0, stream>>>(Wx, WxT, DIM, NGATE);
    transpose_cast<<<dim3(NGATE / 32, HID / 32), tb, 0, stream>>>(Wh, WhT, HID, NGATE);

    // phase 1: all-timestep input GEMM (permuted output)
    gemm_xw<<<dim3(NGATE / 128, MROWS / 128), 256, 0, stream>>>(xbf, WxT, b, Gp);

    // phase 2: persistent recurrence
    lstm_rec<<<NWGR, 512, 0, stream>>>(WhT, Gp, hb, out);
}

// Round 2
// 671.858 us; speedup vs baseline: 1.4823x; 1.4823x over previous
//
#include <hip/hip_runtime.h>
#include <hip/hip_bf16.h>
#include <stdint.h>

// Problem: T=128, B=32, D=1024, H=1024 LSTM unroll, fp32 in/out.
#define T_STEPS 128
#define BATCH   32
#define DIM     1024
#define HID     1024
#define NGATE   4096            // 4*H
#define MROWS   4096            // T*B
#define NWGR    32              // persistent recurrence workgroups

typedef unsigned int u32;
typedef __attribute__((ext_vector_type(8)))  __bf16 bf16x8;
typedef __attribute__((ext_vector_type(4)))  float  f32x4;
typedef __attribute__((ext_vector_type(16))) float  f32x16;
typedef __attribute__((ext_vector_type(4)))  u32    u32x4;

__device__ __forceinline__ unsigned short f2bf(float f) {
    u32 x = __float_as_uint(f);
    return (unsigned short)((x + 0x7fffu + ((x >> 16) & 1u)) >> 16);  // RNE
}
__device__ __forceinline__ float sigf(float x) {
    return 1.0f / (1.0f + __expf(-x));
}
__device__ __forceinline__ float tanh_fast(float x) {
    float ax = fabsf(x);
    float e  = __expf(-2.0f * ax);           // in (0,1], no overflow
    float t  = (1.0f - e) / (1.0f + e);
    return copysignf(t, x);
}
__device__ __forceinline__ u32 umax2(u32 a, u32 b) { return a > b ? a : b; }

// DEVICE-scope (agent) store: sc1 only (gfx94x: SC1:SC0 = 10 = device).
// Bypasses L1 + per-XCD L2, served by the memory-side Infinity Cache.
// hb is ONLY touched through sc1 ops during lstm_rec -> no line of it ever
// lives in any L2 -> no acquire fences / buffer_inv needed anywhere.
__device__ __forceinline__ void store_u32_coh(u32* p, u32 v) {
    asm volatile("global_store_dword %0, %1, off sc1" :: "v"(p), "v"(v) : "memory");
}

// ---------------- prep kernels ----------------

__global__ void cast_f32_bf16(const float* __restrict__ in,
                              unsigned short* __restrict__ out, int n) {
    int idx = (blockIdx.x * blockDim.x + threadIdx.x) * 4;
    if (idx + 3 < n) {
        float4 v = *(const float4*)(in + idx);
        ushort4 o;
        o.x = f2bf(v.x); o.y = f2bf(v.y); o.z = f2bf(v.z); o.w = f2bf(v.w);
        *(ushort4*)(out + idx) = o;
    }
}

// sentinel fill: 0xFFFFFFFF = packed (NaN|NaN) bf16 pair; h is always finite
// and in (-1,1), so a real packed h can never equal the sentinel.
__global__ void fill_sentinel(u32* __restrict__ p, int n) {
    int i = (blockIdx.x * blockDim.x + threadIdx.x) * 4;
    if (i + 3 < n) {
        u32x4 v = {0xFFFFFFFFu, 0xFFFFFFFFu, 0xFFFFFFFFu, 0xFFFFFFFFu};
        *(u32x4*)(p + i) = v;
    }
}

// in: R x C fp32 (row-major) -> out: C x R bf16 (row-major transpose)
__global__ void transpose_cast(const float* __restrict__ in,
                               unsigned short* __restrict__ out, int R, int C) {
    __shared__ float tile[32][33];
    int c0 = blockIdx.x * 32, r0 = blockIdx.y * 32;
    int tx = threadIdx.x, ty = threadIdx.y;     // 32 x 8
#pragma unroll
    for (int i = 0; i < 4; ++i)
        tile[ty + i * 8][tx] = in[(size_t)(r0 + ty + i * 8) * C + c0 + tx];
    __syncthreads();
#pragma unroll
    for (int i = 0; i < 4; ++i)
        out[(size_t)(c0 + ty + i * 8) * R + r0 + tx] = f2bf(tile[tx][ty + i * 8]);
}

// ---------------- phase 1: Gp = perm(x @ Wx + b)  (bf16 MFMA, fp32 out) ----------------
// A: MROWS x DIM bf16 (x), BT: NGATE x DIM bf16 (WxT).
// Output written in recurrence-friendly permuted panels:
//   orig col co = g*1024 + hu  ->  panel wg = hu>>5, local col cp = g*32 + (hu&31)
//   Gp[((wg*MROWS)+row)*128 + cp]
__global__ __launch_bounds__(256) void gemm_xw(
    const unsigned short* __restrict__ A,
    const unsigned short* __restrict__ BT,
    const float* __restrict__ bias,
    float* __restrict__ Gp) {
    __shared__ unsigned short As[128 * 32];
    __shared__ unsigned short Bs[128 * 32];
    int tid  = threadIdx.x;
    int wave = tid >> 6, lane = tid & 63;
    int q = lane >> 4, c = lane & 15;
    int wm = wave >> 1, wn = wave & 1;
    int tm = blockIdx.y * 128, tn = blockIdx.x * 128;

    f32x4 acc[4][4] = {};

    const int srow0 = tid >> 2;           // 0..63
    const int srow1 = 64 + (tid >> 2);    // 64..127
    const int scol  = (tid & 3) * 8;      // bf16 elems

    u32x4 ra0, ra1, rb0, rb1;
    ra0 = *(const u32x4*)(A  + (size_t)(tm + srow0) * DIM + scol);
    ra1 = *(const u32x4*)(A  + (size_t)(tm + srow1) * DIM + scol);
    rb0 = *(const u32x4*)(BT + (size_t)(tn + srow0) * DIM + scol);
    rb1 = *(const u32x4*)(BT + (size_t)(tn + srow1) * DIM + scol);

    for (int kk = 0; kk < 32; ++kk) {
        __syncthreads();
        *(u32x4*)(As + srow0 * 32 + scol) = ra0;
        *(u32x4*)(As + srow1 * 32 + scol) = ra1;
        *(u32x4*)(Bs + srow0 * 32 + scol) = rb0;
        *(u32x4*)(Bs + srow1 * 32 + scol) = rb1;
        __syncthreads();
        if (kk < 31) {
            int ko = (kk + 1) * 32 + scol;
            ra0 = *(const u32x4*)(A  + (size_t)(tm + srow0) * DIM + ko);
            ra1 = *(const u32x4*)(A  + (size_t)(tm + srow1) * DIM + ko);
            rb0 = *(const u32x4*)(BT + (size_t)(tn + srow0) * DIM + ko);
            rb1 = *(const u32x4*)(BT + (size_t)(tn + srow1) * DIM + ko);
        }
        bf16x8 af[4], bfv[4];
#pragma unroll
        for (int i = 0; i < 4; ++i) {
            af[i]  = *(const bf16x8*)(As + (wm * 64 + i * 16 + c) * 32 + q * 8);
            bfv[i] = *(const bf16x8*)(Bs + (wn * 64 + i * 16 + c) * 32 + q * 8);
        }
#pragma unroll
        for (int i = 0; i < 4; ++i)
#pragma unroll
            for (int j = 0; j < 4; ++j)
                acc[i][j] = __builtin_amdgcn_mfma_f32_16x16x32_bf16(
                    af[i], bfv[j], acc[i][j], 0, 0, 0);
    }
    // epilogue: C/D layout col = lane&15, row = quad*4 + reg; permuted store
#pragma unroll
    for (int j = 0; j < 4; ++j) {
        int co = tn + wn * 64 + j * 16 + c;
        float bj = bias[co];
        int g = co >> 10, hu = co & 1023;
        int wgr = hu >> 5, u = hu & 31;
        int cp = g * 32 + u;
#pragma unroll
        for (int i = 0; i < 4; ++i) {
            int row0 = tm + wm * 64 + i * 16 + q * 4;
#pragma unroll
            for (int r = 0; r < 4; ++r)
                Gp[((size_t)wgr * MROWS + row0 + r) * 128 + cp] = acc[i][j][r] + bj;
        }
    }
}

// ---------------- phase 2: persistent recurrence ----------------
// 32 WGs x 512 threads (8 waves). WG wg owns hidden units [wg*32, wg*32+32).
// Wave wv: cg = wv&3 = gate index g (one 32-col tile), ks = wv>>2 (K-half,
// 512 of 1024). Wh fragments (32 x bf16x8) live in registers for all steps.
//
// h-LOAD RESTRUCTURE (R2 theory): the old per-wave h load was 16 instrs each
// touching 32 scattered cache lines (512 line-transactions/wave/round, ~4096
// per CU) -- address-issue serialization ~1.7us per poll round, the dominant
// per-step cost (protocol changes R0->R1 were neutral because both paid it).
// Now: each wave loads its contiguous 8KB slab of h (8x fully-coalesced
// dwordx4, 16 lines each), sentinel-validates in registers, and stages into
// an XOR-swizzled LDS tile Hs[32][1024]. MFMA A-fragments come from
// ds_read_b128 (swizzle: byte ^= (row&15)<<4, same involution on write and
// read). No flags, no producer ack: fire-and-forget sc1 h-stores; each
// consumer wave retries only its own slab until sentinel-free.
// Barriers: A (Hs+nothing-else ready) and B (SlT/Gl ready). The old
// end-of-loop barrier is redundant: epilogue reads at t precede each wave's
// barrier-A arrival at t+1, which gates the next SlT/Gl writes.
__global__ __launch_bounds__(512, 1) void lstm_rec(
    const unsigned short* __restrict__ WhT,   // NGATE x DIM bf16
    const float* __restrict__ Gp,             // permuted gates, 32 x 4096 x 128 fp32
    unsigned short* hb,                       // (T+1) x BATCH x HID bf16 (slot 0 unused)
    float* __restrict__ out) {                // T x BATCH x HID fp32
    __shared__ float Gl[2][32][133];          // double-buffered G slice (pad 133)
    __shared__ float SlT[2][128][33];         // K-split partials, transposed (pad 33)
    __shared__ unsigned short Hs[32][1024];   // h tile, XOR-swizzled rows (64 KB)
    const int wg = blockIdx.x, tid = threadIdx.x;
    const int wv = tid >> 6, lane = tid & 63;
    const int cg = wv & 3, ks = wv >> 2;      // gate tile, K-half
    const int ln = lane & 31, lh = lane >> 5;

    // ---- stage B-fragments (Wh) into registers, once ----
    // B-frag (32x32x16): col = lane&31, k = ks*512 + kk*16 + lh*8 + j
    bf16x8 br[32];
    {
        const unsigned short* w =
            WhT + (size_t)(cg * HID + wg * 32 + ln) * DIM + ks * 512 + lh * 8;
#pragma unroll
        for (int kk = 0; kk < 32; ++kk) br[kk] = *(const bf16x8*)(w + kk * 16);
    }

    // ---- G slice for t=0 into Gl[0] ----
    {
        const float* p = Gp + (size_t)wg * MROWS * 128 + tid * 8;
        f32x4 a = *(const f32x4*)p, b2 = *(const f32x4*)(p + 4);
        float* d = &Gl[0][tid >> 4][(tid & 15) * 8];
#pragma unroll
        for (int i = 0; i < 4; ++i) { d[i] = a[i]; d[4 + i] = b2[i]; }
    }
    __syncthreads();

    // epilogue mapping: thread = (batch, uu); owns units 2*uu, 2*uu+1
    const int batch = tid >> 4, uu = tid & 15;
    float cs0 = 0.f, cs1 = 0.f;
    f32x4 ga = {}, gb = {};

    char* hs_base = (char*)&Hs[0][0];
    const int rxor = (ln & 15) << 4;          // read-side swizzle constant

    for (int t = 0; t < T_STEPS; ++t) {
        const int cur = t & 1;

        f32x16 accA = {}, accB = {};
        if (t > 0) {
            // ---- coalesced, sentinel-validated h load (wave-local retry) ----
            // flat byte layout of slot t: batch*2048 + unit*2 (row-major).
            // wave wv owns bytes [wv*8K, wv*8K+8K): 8 instrs x 1KB contiguous.
            const char* p0 = (const char*)hb + ((size_t)t << 16)
                           + ((size_t)wv << 13) + (size_t)lane * 16;
            const char* p1 = p0 + 4096;
            u32x4 h[8];
            for (;;) {
                asm volatile(
                    "global_load_dwordx4 %0, %8, off sc1\n\t"
                    "global_load_dwordx4 %1, %8, off offset:1024 sc1\n\t"
                    "global_load_dwordx4 %2, %8, off offset:2048 sc1\n\t"
                    "global_load_dwordx4 %3, %8, off offset:3072 sc1\n\t"
                    "global_load_dwordx4 %4, %9, off sc1\n\t"
                    "global_load_dwordx4 %5, %9, off offset:1024 sc1\n\t"
                    "global_load_dwordx4 %6, %9, off offset:2048 sc1\n\t"
                    "global_load_dwordx4 %7, %9, off offset:3072 sc1\n\t"
                    "s_waitcnt vmcnt(0)"
                    : "=&v"(h[0]), "=&v"(h[1]), "=&v"(h[2]), "=&v"(h[3]),
                      "=&v"(h[4]), "=&v"(h[5]), "=&v"(h[6]), "=&v"(h[7])
                    : "v"(p0), "v"(p1)
                    : "memory");
                u32 m = 0;
#pragma unroll
                for (int i = 0; i < 8; ++i) {
                    u32 a = umax2(umax2(h[i][0], h[i][1]),
                                  umax2(h[i][2], h[i][3]));
                    m = umax2(m, a);
                }
                if (!__any((int)(m == 0xFFFFFFFFu))) break;
            }
            // ---- stage into swizzled LDS: chunk j = bytes wv*8K + lane*16 + j*1K ----
            // row = wv*4 + (j>>1); colb = (j&1)*1024 + lane*16;
            // lds byte = row*2048 + (colb ^ ((row&15)<<4))
#pragma unroll
            for (int j = 0; j < 8; ++j) {
                int row  = (wv << 2) + (j >> 1);
                int colb = ((j & 1) << 10) + lane * 16;
                int off  = (row << 11) + (colb ^ ((row & 15) << 4));
                *(u32x4*)(hs_base + off) = h[j];
            }
            asm volatile("s_waitcnt lgkmcnt(0)" ::: "memory");
            __builtin_amdgcn_s_barrier();            // barrier A: Hs ready

            // ---- fragments from LDS + 32 MFMAs (two 16-deep chains) ----
            // A-frag (32x32x16): row = lane&31, k = kbase + lh*8 + j
            const char* hrow = hs_base + (ln << 11);
#pragma unroll
            for (int kk = 0; kk < 16; ++kk) {
                int c0 = ((ks << 10) + (kk << 5) + (lh << 4)) ^ rxor;
                int c1 = ((ks << 10) + ((kk + 16) << 5) + (lh << 4)) ^ rxor;
                bf16x8 a0 = *(const bf16x8*)(hrow + c0);
                bf16x8 a1 = *(const bf16x8*)(hrow + c1);
                accA = __builtin_amdgcn_mfma_f32_32x32x16_bf16(a0, br[kk],      accA, 0, 0, 0);
                accB = __builtin_amdgcn_mfma_f32_32x32x16_bf16(a1, br[kk + 16], accB, 0, 0, 0);
            }
        }

        // ---- K-split partials into LDS (scalar, conflict-free at pad 33) ----
        // C layout 32x32: col = lane&31, row = (reg&3) + 8*(reg>>2) + 4*(lane>>5)
#pragma unroll
        for (int rg = 0; rg < 4; ++rg)
#pragma unroll
            for (int rr = 0; rr < 4; ++rr)
                SlT[ks][(cg << 5) + ln][rg * 8 + lh * 4 + rr] =
                    accA[rg * 4 + rr] + accB[rg * 4 + rr];
        if (t > 0) {   // Gl[cur] for t==0 was pre-filled; ga/gb holds slice t
            float* d = &Gl[cur][tid >> 4][(tid & 15) * 8];
#pragma unroll
            for (int i = 0; i < 4; ++i) { d[i] = ga[i]; d[4 + i] = gb[i]; }
        }
        asm volatile("s_waitcnt lgkmcnt(0)" ::: "memory");
        __builtin_amdgcn_s_barrier();                // barrier B: SlT/Gl ready

        // ---- epilogue: units u0 = 2*uu, u1 = 2*uu+1 of batch ----
        float gv0[4], gv1[4];
#pragma unroll
        for (int g = 0; g < 4; ++g) {
            const int c0 = g * 32 + 2 * uu, c1 = c0 + 1;
            gv0[g] = Gl[cur][batch][c0] + SlT[0][c0][batch] + SlT[1][c0][batch];
            gv1[g] = Gl[cur][batch][c1] + SlT[0][c1][batch] + SlT[1][c1][batch];
        }
        float cn0 = sigf(gv0[1]) * cs0 + sigf(gv0[0]) * tanh_fast(gv0[2]);
        float cn1 = sigf(gv1[1]) * cs1 + sigf(gv1[0]) * tanh_fast(gv1[2]);
        cs0 = cn0; cs1 = cn1;
        float hv0 = sigf(gv0[3]) * tanh_fast(cn0);
        float hv1 = sigf(gv1[3]) * tanh_fast(cn1);
        u32 packed = (u32)f2bf(hv0) | ((u32)f2bf(hv1) << 16);
        // broadcast h: fire-and-forget sc1 store; consumers self-validate.
        store_u32_coh((u32*)(hb + (size_t)(t + 1) * (BATCH * HID)
                                + (size_t)batch * HID + wg * 32 + 2 * uu), packed);

        // off the critical path: G prefetch for step t+1 + out-store
        if (t + 1 < T_STEPS) {
            const float* p = Gp + ((size_t)wg * MROWS + (size_t)(t + 1) * 32) * 128 + tid * 8;
            ga = *(const f32x4*)p; gb = *(const f32x4*)(p + 4);
        }
        *(float2*)(out + ((size_t)t * BATCH + batch) * HID + wg * 32 + 2 * uu) =
            make_float2(hv0, hv1);
        // no end-of-loop barrier needed: next iteration's first LDS writes (Hs)
        // are disjoint from SlT/Gl, and its SlT/Gl writes sit behind barrier A.
    }
}

// ---------------- launch ----------------

extern "C" void kernel_launch(void* const* d_in, const int* in_sizes, int n_in,
                              void* d_out, int out_size, void* d_ws, size_t ws_size,
                              hipStream_t stream) {
    const float* x  = (const float*)d_in[0];   // T*B*D
    const float* Wx = (const float*)d_in[1];   // D x 4H
    const float* Wh = (const float*)d_in[2];   // H x 4H
    const float* b  = (const float*)d_in[3];   // 4H
    float* out = (float*)d_out;

    // workspace layout (bytes)
    char* ws = (char*)d_ws;
    const size_t OFF_XBF  = 0;                       // 8 MB  (4096x1024 bf16)
    const size_t OFF_WXT  = 8ull  << 20;             // 8 MB  (4096x1024 bf16)
    const size_t OFF_WHT  = 16ull << 20;             // 8 MB  (4096x1024 bf16)
    const size_t OFF_G    = 24ull << 20;             // 64 MB (32x4096x128 fp32 permuted)
    const size_t OFF_HB   = 88ull << 20;             // 129 * 64 KB = 8.0625 MB
    const size_t NEEDED   = OFF_HB + (size_t)(T_STEPS + 1) * BATCH * HID * 2;
    if (ws_size < NEEDED) return;  // loud failure (output stays poisoned)

    unsigned short* xbf = (unsigned short*)(ws + OFF_XBF);
    unsigned short* WxT = (unsigned short*)(ws + OFF_WXT);
    unsigned short* WhT = (unsigned short*)(ws + OFF_WHT);
    float*          Gp  = (float*)(ws + OFF_G);
    unsigned short* hb  = (unsigned short*)(ws + OFF_HB);

    // prep
    cast_f32_bf16<<<(MROWS * DIM / 4 + 255) / 256, 256, 0, stream>>>(x, xbf, MROWS * DIM);
    const int HBW = (T_STEPS + 1) * BATCH * HID / 2;    // u32 words in hb
    fill_sentinel<<<(HBW / 4 + 255) / 256, 256, 0, stream>>>((u32*)hb, HBW);
    dim3 tb(32, 8);
    transpose_cast<<<dim3(NGATE / 32, DIM / 32), tb, 0, stream>>>(Wx, WxT, DIM, NGATE);
    transpose_cast<<<dim3(NGATE / 32, HID / 32), tb, 0, stream>>>(Wh, WhT, HID, NGATE);

    // phase 1: all-timestep input GEMM (permuted output)
    gemm_xw<<<dim3(NGATE / 128, MROWS / 128), 256, 0, stream>>>(xbf, WxT, b, Gp);

    // phase 2: persistent recurrence
    lstm_rec<<<NWGR, 512, 0, stream>>>(WhT, Gp, hb, out);
}

// Round 3
// 495.727 us; speedup vs baseline: 2.0090x; 1.3553x over previous
//
#include <hip/hip_runtime.h>
#include <hip/hip_bf16.h>
#include <stdint.h>

// Problem: T=128, B=32, D=1024, H=1024 LSTM unroll, fp32 in/out.
#define T_STEPS 128
#define BATCH   32
#define DIM     1024
#define HID     1024
#define NGATE   4096            // 4*H
#define MROWS   4096            // T*B
#define NWGR    64              // persistent recurrence workgroups (16 units each)

typedef unsigned int u32;
typedef __attribute__((ext_vector_type(8)))  __bf16 bf16x8;
typedef __attribute__((ext_vector_type(4)))  float  f32x4;
typedef __attribute__((ext_vector_type(16))) float  f32x16;
typedef __attribute__((ext_vector_type(4)))  u32    u32x4;

__device__ __forceinline__ unsigned short f2bf(float f) {
    u32 x = __float_as_uint(f);
    return (unsigned short)((x + 0x7fffu + ((x >> 16) & 1u)) >> 16);  // RNE
}
__device__ __forceinline__ float sigf(float x) {
    return 1.0f / (1.0f + __expf(-x));
}
__device__ __forceinline__ float tanh_fast(float x) {
    float ax = fabsf(x);
    float e  = __expf(-2.0f * ax);           // in (0,1], no overflow
    float t  = (1.0f - e) / (1.0f + e);
    return copysignf(t, x);
}
__device__ __forceinline__ u32 umax2(u32 a, u32 b) { return a > b ? a : b; }

// DEVICE-scope (agent) store: sc1 only. Bypasses L1 + per-XCD L2, served by
// the memory-side Infinity Cache. hb is ONLY touched through sc1 ops during
// lstm_rec -> no line of it ever lives in any L2 -> no fences needed.
__device__ __forceinline__ void store_u32_coh(u32* p, u32 v) {
    asm volatile("global_store_dword %0, %1, off sc1" :: "v"(p), "v"(v) : "memory");
}

// ---------------- prep kernels ----------------

__global__ void cast_f32_bf16(const float* __restrict__ in,
                              unsigned short* __restrict__ out, int n) {
    int idx = (blockIdx.x * blockDim.x + threadIdx.x) * 4;
    if (idx + 3 < n) {
        float4 v = *(const float4*)(in + idx);
        ushort4 o;
        o.x = f2bf(v.x); o.y = f2bf(v.y); o.z = f2bf(v.z); o.w = f2bf(v.w);
        *(ushort4*)(out + idx) = o;
    }
}

// sentinel fill: 0xFFFFFFFF = packed (NaN|NaN) bf16 pair; h is always finite
// and in (-1,1), so a real packed h can never equal the sentinel.
__global__ void fill_sentinel(u32* __restrict__ p, int n) {
    int i = (blockIdx.x * blockDim.x + threadIdx.x) * 4;
    if (i + 3 < n) {
        u32x4 v = {0xFFFFFFFFu, 0xFFFFFFFFu, 0xFFFFFFFFu, 0xFFFFFFFFu};
        *(u32x4*)(p + i) = v;
    }
}

// in: R x C fp32 (row-major) -> out: C x R bf16 (row-major transpose)
__global__ void transpose_cast(const float* __restrict__ in,
                               unsigned short* __restrict__ out, int R, int C) {
    __shared__ float tile[32][33];
    int c0 = blockIdx.x * 32, r0 = blockIdx.y * 32;
    int tx = threadIdx.x, ty = threadIdx.y;     // 32 x 8
#pragma unroll
    for (int i = 0; i < 4; ++i)
        tile[ty + i * 8][tx] = in[(size_t)(r0 + ty + i * 8) * C + c0 + tx];
    __syncthreads();
#pragma unroll
    for (int i = 0; i < 4; ++i)
        out[(size_t)(c0 + ty + i * 8) * R + r0 + tx] = f2bf(tile[tx][ty + i * 8]);
}

// ---------------- phase 1: Gp = perm(x @ Wx + b)  (bf16 MFMA, fp32 out) ----------------
// A: MROWS x DIM bf16 (x), BT: NGATE x DIM bf16 (WxT).
// Output in GATE-MINOR panels for the 64-WG recurrence:
//   orig col co = g*1024 + hu  ->  panel wg = hu>>4 (16 units), local unit u = hu&15,
//   panel col cp = u*4 + g  (so 4 gates of a unit are CONTIGUOUS -> f32x4 epilogue)
//   Gp[((size_t)wg*MROWS + row)*64 + cp]
__global__ __launch_bounds__(256) void gemm_xw(
    const unsigned short* __restrict__ A,
    const unsigned short* __restrict__ BT,
    const float* __restrict__ bias,
    float* __restrict__ Gp) {
    __shared__ unsigned short As[128 * 32];
    __shared__ unsigned short Bs[128 * 32];
    int tid  = threadIdx.x;
    int wave = tid >> 6, lane = tid & 63;
    int q = lane >> 4, c = lane & 15;
    int wm = wave >> 1, wn = wave & 1;
    int tm = blockIdx.y * 128, tn = blockIdx.x * 128;

    f32x4 acc[4][4] = {};

    const int srow0 = tid >> 2;           // 0..63
    const int srow1 = 64 + (tid >> 2);    // 64..127
    const int scol  = (tid & 3) * 8;      // bf16 elems

    u32x4 ra0, ra1, rb0, rb1;
    ra0 = *(const u32x4*)(A  + (size_t)(tm + srow0) * DIM + scol);
    ra1 = *(const u32x4*)(A  + (size_t)(tm + srow1) * DIM + scol);
    rb0 = *(const u32x4*)(BT + (size_t)(tn + srow0) * DIM + scol);
    rb1 = *(const u32x4*)(BT + (size_t)(tn + srow1) * DIM + scol);

    for (int kk = 0; kk < 32; ++kk) {
        __syncthreads();
        *(u32x4*)(As + srow0 * 32 + scol) = ra0;
        *(u32x4*)(As + srow1 * 32 + scol) = ra1;
        *(u32x4*)(Bs + srow0 * 32 + scol) = rb0;
        *(u32x4*)(Bs + srow1 * 32 + scol) = rb1;
        __syncthreads();
        if (kk < 31) {
            int ko = (kk + 1) * 32 + scol;
            ra0 = *(const u32x4*)(A  + (size_t)(tm + srow0) * DIM + ko);
            ra1 = *(const u32x4*)(A  + (size_t)(tm + srow1) * DIM + ko);
            rb0 = *(const u32x4*)(BT + (size_t)(tn + srow0) * DIM + ko);
            rb1 = *(const u32x4*)(BT + (size_t)(tn + srow1) * DIM + ko);
        }
        bf16x8 af[4], bfv[4];
#pragma unroll
        for (int i = 0; i < 4; ++i) {
            af[i]  = *(const bf16x8*)(As + (wm * 64 + i * 16 + c) * 32 + q * 8);
            bfv[i] = *(const bf16x8*)(Bs + (wn * 64 + i * 16 + c) * 32 + q * 8);
        }
#pragma unroll
        for (int i = 0; i < 4; ++i)
#pragma unroll
            for (int j = 0; j < 4; ++j)
                acc[i][j] = __builtin_amdgcn_mfma_f32_16x16x32_bf16(
                    af[i], bfv[j], acc[i][j], 0, 0, 0);
    }
    // epilogue: C/D layout col = lane&15, row = quad*4 + reg; gate-minor store
#pragma unroll
    for (int j = 0; j < 4; ++j) {
        int co = tn + wn * 64 + j * 16 + c;
        float bj = bias[co];
        int g = co >> 10, hu = co & 1023;
        int wgr = hu >> 4, u = hu & 15;
        int cp = u * 4 + g;
#pragma unroll
        for (int i = 0; i < 4; ++i) {
            int row0 = tm + wm * 64 + i * 16 + q * 4;
#pragma unroll
            for (int r = 0; r < 4; ++r)
                Gp[((size_t)wgr * MROWS + row0 + r) * 64 + cp] = acc[i][j][r] + bj;
        }
    }
}

// ---------------- phase 2: persistent recurrence ----------------
// 64 WGs x 512 threads (8 waves). WG wg owns 16 hidden units -> 64 gate-minor
// panel cols (2 MFMA col-tiles of 32). Wave wv = K-EIGHTH ks (128 k), and
// computes BOTH tiles from each A-fragment read -> zero A-read redundancy
// (R2 had 4x: per-CU A-traffic 256KB -> 64KB). Per-CU LDS/step ~200KB vs
// ~450KB in R2, and 64 CUs active instead of 32.
// Sentinel protocol, slab staging, and Hs XOR-swizzle are UNCHANGED from R2.
// Barriers: A (Hs ready), B (SlT ready; also orders Hs(t) reads vs stage(t+1)
// writes). Cross-step ordering comes free from sentinel gating: a wave can
// only overwrite Hs(t+1) after validating h(t+1), which requires every wave's
// h-store(t+1), which is after every wave's Hs(t)/SlT(t) reads.
__global__ __launch_bounds__(512, 1) void lstm_rec(
    const unsigned short* __restrict__ WhT,   // NGATE x DIM bf16
    const float* __restrict__ Gp,             // gate-minor panels, 64 x 4096 x 64 fp32
    unsigned short* hb,                       // (T+1) x BATCH x HID bf16 (slot 0 unused)
    float* __restrict__ out) {                // T x BATCH x HID fp32
    __shared__ unsigned short Hs[32][1024];   // h tile, XOR-swizzled rows (64 KB)
    __shared__ float SlT[8][32][64];          // K-eighth partials [ks][b][panel col] (64 KB)
    __shared__ unsigned short Ht[32][16];     // h bf16 pack tile (1 KB)
    const int wg = blockIdx.x, tid = threadIdx.x;
    const int wv = tid >> 6, lane = tid & 63;
    const int ln = lane & 31, lh = lane >> 5;

    // ---- stage B-fragments (Wh) into registers, once ----
    // B-frag (32x32x16): col = lane&31 = u8*4+g (gate-minor), k = wv*128 + kk*16 + lh*8 + j
    bf16x8 br0[8], br1[8];
    {
        const int u8 = ln >> 2, g = ln & 3;
        const unsigned short* w0 =
            WhT + (size_t)(g * HID + wg * 16 + 0 * 8 + u8) * DIM + wv * 128 + lh * 8;
        const unsigned short* w1 =
            WhT + (size_t)(g * HID + wg * 16 + 1 * 8 + u8) * DIM + wv * 128 + lh * 8;
#pragma unroll
        for (int kk = 0; kk < 8; ++kk) {
            br0[kk] = *(const bf16x8*)(w0 + kk * 16);
            br1[kk] = *(const bf16x8*)(w1 + kk * 16);
        }
    }

    // epilogue mapping: thread = (batch, u); ONE output per thread
    const int batch = tid >> 4, uu = tid & 15;
    float cs = 0.f;
    // G prefetch for t=0 (gate-minor: f32x4 = 4 gates of unit uu)
    f32x4 ga = *(const f32x4*)(Gp + ((size_t)wg * MROWS + batch) * 64 + uu * 4);

    char* hs_base = (char*)&Hs[0][0];
    const int rxor = (ln & 15) << 4;          // read-side swizzle constant

    for (int t = 0; t < T_STEPS; ++t) {
        if (t > 0) {
            // ---- coalesced, sentinel-validated h load (wave-local retry) ----
            // flat byte layout of slot t: batch*2048 + unit*2 (row-major).
            // wave wv owns bytes [wv*8K, wv*8K+8K): 8 instrs x 1KB contiguous.
            const char* p0 = (const char*)hb + ((size_t)t << 16)
                           + ((size_t)wv << 13) + (size_t)lane * 16;
            const char* p1 = p0 + 4096;
            u32x4 h[8];
            for (;;) {
                asm volatile(
                    "global_load_dwordx4 %0, %8, off sc1\n\t"
                    "global_load_dwordx4 %1, %8, off offset:1024 sc1\n\t"
                    "global_load_dwordx4 %2, %8, off offset:2048 sc1\n\t"
                    "global_load_dwordx4 %3, %8, off offset:3072 sc1\n\t"
                    "global_load_dwordx4 %4, %9, off sc1\n\t"
                    "global_load_dwordx4 %5, %9, off offset:1024 sc1\n\t"
                    "global_load_dwordx4 %6, %9, off offset:2048 sc1\n\t"
                    "global_load_dwordx4 %7, %9, off offset:3072 sc1\n\t"
                    "s_waitcnt vmcnt(0)"
                    : "=&v"(h[0]), "=&v"(h[1]), "=&v"(h[2]), "=&v"(h[3]),
                      "=&v"(h[4]), "=&v"(h[5]), "=&v"(h[6]), "=&v"(h[7])
                    : "v"(p0), "v"(p1)
                    : "memory");
                u32 m = 0;
#pragma unroll
                for (int i = 0; i < 8; ++i) {
                    u32 a = umax2(umax2(h[i][0], h[i][1]),
                                  umax2(h[i][2], h[i][3]));
                    m = umax2(m, a);
                }
                if (!__any((int)(m == 0xFFFFFFFFu))) break;
            }
            // ---- stage into swizzled LDS (R2 formula, unchanged) ----
#pragma unroll
            for (int j = 0; j < 8; ++j) {
                int row  = (wv << 2) + (j >> 1);
                int colb = ((j & 1) << 10) + lane * 16;
                int off  = (row << 11) + (colb ^ ((row & 15) << 4));
                *(u32x4*)(hs_base + off) = h[j];
            }
            asm volatile("s_waitcnt lgkmcnt(0)" ::: "memory");
            __builtin_amdgcn_s_barrier();            // barrier A: Hs ready

            // ---- K-eighth: 8 A-reads, 16 MFMAs (each read feeds BOTH tiles) ----
            // A-frag (32x32x16): row = lane&31 (batch), k = wv*128 + kk*16 + lh*8 + j
            f32x16 acc0 = {}, acc1 = {};
            const char* hrow = hs_base + (ln << 11);
#pragma unroll
            for (int kk = 0; kk < 8; ++kk) {
                int cb = ((wv << 8) + (kk << 5) + (lh << 4)) ^ rxor;
                bf16x8 a = *(const bf16x8*)(hrow + cb);
                acc0 = __builtin_amdgcn_mfma_f32_32x32x16_bf16(a, br0[kk], acc0, 0, 0, 0);
                acc1 = __builtin_amdgcn_mfma_f32_32x32x16_bf16(a, br1[kk], acc1, 0, 0, 0);
            }

            // ---- dump partials: SlT[ks][b][col], banks = ln -> conflict-free ----
            // C layout 32x32: col = lane&31, b = (reg&3) + 8*(reg>>2) + 4*(lane>>5)
#pragma unroll
            for (int rg = 0; rg < 4; ++rg)
#pragma unroll
                for (int rr = 0; rr < 4; ++rr) {
                    const int bb = rg * 8 + lh * 4 + rr;
                    SlT[wv][bb][ln]      = acc0[rg * 4 + rr];
                    SlT[wv][bb][32 + ln] = acc1[rg * 4 + rr];
                }
            asm volatile("s_waitcnt lgkmcnt(0)" ::: "memory");
            __builtin_amdgcn_s_barrier();            // barrier B: SlT ready
        }

        // ---- epilogue: ONE output (batch, unit uu) per thread ----
        f32x4 gv = ga;                               // gates i,f,g,o of unit uu
        if (t > 0) {
#pragma unroll
            for (int ks = 0; ks < 8; ++ks)
                gv += *(const f32x4*)&SlT[ks][batch][uu * 4];
        }
        float cn = sigf(gv[1]) * cs + sigf(gv[0]) * tanh_fast(gv[2]);
        cs = cn;
        float hv = sigf(gv[3]) * tanh_fast(cn);

        // pack h pairs via in-wave LDS bounce (Ht rows 4b per wave: in-wave only)
        Ht[batch][uu] = f2bf(hv);
        asm volatile("s_waitcnt lgkmcnt(0)" ::: "memory");
        if ((uu & 1) == 0) {
            u32 packed = *(const u32*)&Ht[batch][uu];
            store_u32_coh((u32*)(hb + (size_t)(t + 1) * (BATCH * HID)
                                    + (size_t)batch * HID + wg * 16 + uu), packed);
        }

        // off the critical path: G prefetch for step t+1 + out-store
        if (t + 1 < T_STEPS)
            ga = *(const f32x4*)(Gp + ((size_t)wg * MROWS + (size_t)(t + 1) * 32 + batch) * 64
                                 + uu * 4);
        out[((size_t)t * BATCH + batch) * HID + wg * 16 + uu] = hv;
        // no end-of-loop barrier: stage(t+1) Hs writes are sentinel-gated behind
        // every wave's h-store(t+1), which follows its SlT/Hs reads of step t.
    }
}

// ---------------- launch ----------------

extern "C" void kernel_launch(void* const* d_in, const int* in_sizes, int n_in,
                              void* d_out, int out_size, void* d_ws, size_t ws_size,
                              hipStream_t stream) {
    const float* x  = (const float*)d_in[0];   // T*B*D
    const float* Wx = (const float*)d_in[1];   // D x 4H
    const float* Wh = (const float*)d_in[2];   // H x 4H
    const float* b  = (const float*)d_in[3];   // 4H
    float* out = (float*)d_out;

    // workspace layout (bytes)
    char* ws = (char*)d_ws;
    const size_t OFF_XBF  = 0;                       // 8 MB  (4096x1024 bf16)
    const size_t OFF_WXT  = 8ull  << 20;             // 8 MB  (4096x1024 bf16)
    const size_t OFF_WHT  = 16ull << 20;             // 8 MB  (4096x1024 bf16)
    const size_t OFF_G    = 24ull << 20;             // 64 MB (64x4096x64 fp32 gate-minor)
    const size_t OFF_HB   = 88ull << 20;             // 129 * 64 KB = 8.0625 MB
    const size_t NEEDED   = OFF_HB + (size_t)(T_STEPS + 1) * BATCH * HID * 2;
    if (ws_size < NEEDED) return;  // loud failure (output stays poisoned)

    unsigned short* xbf = (unsigned short*)(ws + OFF_XBF);
    unsigned short* WxT = (unsigned short*)(ws + OFF_WXT);
    unsigned short* WhT = (unsigned short*)(ws + OFF_WHT);
    float*          Gp  = (float*)(ws + OFF_G);
    unsigned short* hb  = (unsigned short*)(ws + OFF_HB);

    // prep
    cast_f32_bf16<<<(MROWS * DIM / 4 + 255) / 256, 256, 0, stream>>>(x, xbf, MROWS * DIM);
    const int HBW = (T_STEPS + 1) * BATCH * HID / 2;    // u32 words in hb
    fill_sentinel<<<(HBW / 4 + 255) / 256, 256, 0, stream>>>((u32*)hb, HBW);
    dim3 tb(32, 8);
    transpose_cast<<<dim3(NGATE / 32, DIM / 32), tb, 0, stream>>>(Wx, WxT, DIM, NGATE);
    transpose_cast<<<dim3(NGATE / 32, HID / 32), tb, 0, stream>>>(Wh, WhT, HID, NGATE);

    // phase 1: all-timestep input GEMM (gate-minor permuted output)
    gemm_xw<<<dim3(NGATE / 128, MROWS / 128), 256, 0, stream>>>(xbf, WxT, b, Gp);

    // phase 2: persistent recurrence
    lstm_rec<<<NWGR, 512, 0, stream>>>(WhT, Gp, hb, out);
}